// Round 1
// baseline (122.338 us; speedup 1.0000x reference)
//
#include <hip/hip_runtime.h>
#include <hip/hip_bf16.h>
#include <hip/hip_fp8.h>
#include <math.h>

typedef __attribute__((ext_vector_type(4))) int   int4v;
typedef __attribute__((ext_vector_type(8))) int   int8v;
typedef __attribute__((ext_vector_type(4))) float f32x4;

#define BM 128
#define BN 128
#define BK 128   // fp8: one 16x16x128 MFMA consumes the whole staged K-slab

union frag_u { int8v v; int4v h[2]; };

// ---------------------------------------------------------------------------
// prep: 2048 blocks x 256 threads (8 waves/SIMD), one wave per row per iter.
// fp32 -> fp8 e4m3 (OCP) via HW v_cvt_pk_fp8_f32 + exact fp32 ||row||^2.
// Also zeroes rowsum[M].
// ---------------------------------------------------------------------------
__global__ __launch_bounds__(256) void prep_kernel(
    const float* __restrict__ X, const float* __restrict__ S,
    unsigned char* __restrict__ Xq, unsigned char* __restrict__ Sq,
    float* __restrict__ x2, float* __restrict__ s2,
    float* __restrict__ rowsum, int M, int R, int Dv)
{
    const int gid  = blockIdx.x * 256 + threadIdx.x;
    const int nthr = gridDim.x * 256;

    for (int i = gid; i < M; i += nthr) rowsum[i] = 0.f;

    const int lane = threadIdx.x & 63;
    const int wid  = gid >> 6;
    const int nw   = nthr >> 6;

    for (int row = wid; row < R; row += nw) {
        const float* rp;
        unsigned char* op;
        float* sq;
        if (row < M) { rp = X + (size_t)row * Dv;       op = Xq + (size_t)row * Dv;       sq = x2 + row; }
        else         { rp = S + (size_t)(row - M) * Dv; op = Sq + (size_t)(row - M) * Dv; sq = s2 + (row - M); }

        float acc = 0.f;
        for (int k = lane * 8; k < Dv; k += 64 * 8) {
            float4 v0 = *(const float4*)(rp + k);
            float4 v1 = *(const float4*)(rp + k + 4);
            acc += v0.x * v0.x + v0.y * v0.y + v0.z * v0.z + v0.w * v0.w;
            acc += v1.x * v1.x + v1.y * v1.y + v1.z * v1.z + v1.w * v1.w;
            // HW packed fp8 e4m3 (OCP) conversion: 4 instrs per 8 floats, RNE+sat
            int lo = __builtin_amdgcn_cvt_pk_fp8_f32(v0.x, v0.y, 0, false);
            lo     = __builtin_amdgcn_cvt_pk_fp8_f32(v0.z, v0.w, lo, true);
            int hi = __builtin_amdgcn_cvt_pk_fp8_f32(v1.x, v1.y, 0, false);
            hi     = __builtin_amdgcn_cvt_pk_fp8_f32(v1.z, v1.w, hi, true);
            union { int i2[2]; uint2 u; } pk;
            pk.i2[0] = lo; pk.i2[1] = hi;
            *(uint2*)(op + k) = pk.u;
        }
#pragma unroll
        for (int off = 1; off < 64; off <<= 1)
            acc += __shfl_xor(acc, off, 64);
        if (lane == 0) *sq = acc;
    }
}

// ---------------------------------------------------------------------------
// Fused fp8 GEMM + exp-reduce. 256 threads (4 waves 2x2), tile 128x128,
// BK=128, mfma_scale 16x16x128 f8f6f4 with unity E8M0 scales.
// NEW vs prior round: double-buffered LDS (2 x 32KB) + raw s_barrier with
// COUNTED vmcnt(8) so the slab-(t+2) global_load_lds stay in flight across
// barriers and their latency hides under the 16 MFMAs (T3/T4-lite).
// Fragment ds_reads land directly in int8v storage (no v_mov assembly).
// Swizzle, fragment layout, MFMA and epilogue identical to verified kernel.
//
// Pipeline (NT = D/128 slabs, buffer b = t&1):
//   prologue: stage(slab0->buf0), stage(slab1->buf1)        (8+8 loads/wave)
//   iter t:   vmcnt(8) [slab t landed; t+1 still flying]; s_barrier
//             ds_read 8 frags from buf[t&1]
//             if t+2<NT: lgkmcnt(0); s_barrier  [reads done before overwrite]
//                        stage(slab t+2 -> buf[t&1])        (+8 loads, async)
//             16x MFMA   [hides the in-flight loads]
//   last iter waits vmcnt(0).
// ---------------------------------------------------------------------------
template<int DVC>
__global__ __launch_bounds__(256, 2) void kde_gemm_kernel(
    const unsigned char* __restrict__ Xq,   // [M][D] fp8 e4m3
    const unsigned char* __restrict__ Sq,   // [N][D] fp8 e4m3
    const float* __restrict__ x2,
    const float* __restrict__ s2,
    const float* __restrict__ scale_p,
    float* __restrict__ rowsum,
    int M, int N, int Dv)
{
    const int D  = DVC ? DVC : Dv;
    const int NT = D / BK;

    __shared__ char smem[65536];   // 2 buffers x (As 16KB + Bs 16KB)

    const int tid  = threadIdx.x;
    const int wave = tid >> 6;
    const int lane = tid & 63;
    const int quad = lane >> 4;
    const int l16  = lane & 15;

    const int m0 = blockIdx.x * BM;
    const int n0 = blockIdx.y * BN;
    const int wm = (wave & 1) * 64;   // wave's 64x64 quadrant
    const int wn = (wave >> 1) * 64;

    const float sc = *scale_p;

    f32x4 acc[4][4] = {};

    // staging: thread t stages row wave*8+(lane>>3)+rd*32, global 16B-chunk
    // (lane&7)^(row&7) into linear LDS slot (satisfies global_load_lds
    // linear-lane rule; XOR-chunk swizzle lives in the global source addr).
    const int srow0 = wave * 8 + (lane >> 3);
    const int cg    = (lane & 7) ^ (lane >> 3);   // (row&7) == lane>>3
    const unsigned char* gA = Xq + (size_t)(m0 + srow0) * D + cg * 16;
    const unsigned char* gB = Sq + (size_t)(n0 + srow0) * D + cg * 16;

    auto stage = [&](int slab, int bufo) {
        const size_t ko = (size_t)slab * BK;
#pragma unroll
        for (int rd = 0; rd < 4; ++rd) {
            __builtin_amdgcn_global_load_lds(
                (const __attribute__((address_space(1))) void*)(gA + (size_t)rd * 32 * D + ko),
                (__attribute__((address_space(3))) void*)(smem + bufo + rd * 4096 + wave * 1024),
                16, 0, 0);
            __builtin_amdgcn_global_load_lds(
                (const __attribute__((address_space(1))) void*)(gB + (size_t)rd * 32 * D + ko),
                (__attribute__((address_space(3))) void*)(smem + bufo + 16384 + rd * 4096 + wave * 1024),
                16, 0, 0);
        }
    };

    stage(0, 0);
    if (NT > 1) stage(1, 32768);

    // ds_read addresses: k0-invariant; after unroll these collapse to
    // 2 base VGPRs + 16-bit immediates (all offsets < 65536).
    const int e     = l16 & 7;
    const int offLo = ((2 * quad)     ^ e) * 16;
    const int offHi = ((2 * quad + 1) ^ e) * 16;
    int aOff[4], bOff[4];
#pragma unroll
    for (int i = 0; i < 4; ++i) {
        aOff[i] = (wm + i * 16 + l16) * 128;
        bOff[i] = 16384 + (wn + i * 16 + l16) * 128;
    }

#pragma unroll
    for (int t = 0; t < NT; ++t) {
        // slab t resident in buf[t&1]; slab t+1's 8 loads may still fly
        if (t + 1 < NT) asm volatile("s_waitcnt vmcnt(8)" ::: "memory");
        else            asm volatile("s_waitcnt vmcnt(0)" ::: "memory");
        __builtin_amdgcn_s_barrier();

        const int bufo = (t & 1) * 32768;
        frag_u a_frag[4], b_frag[4];
#pragma unroll
        for (int mi = 0; mi < 4; ++mi) {
            a_frag[mi].h[0] = *(const int4v*)(smem + bufo + aOff[mi] + offLo);
            a_frag[mi].h[1] = *(const int4v*)(smem + bufo + aOff[mi] + offHi);
        }
#pragma unroll
        for (int ni = 0; ni < 4; ++ni) {
            b_frag[ni].h[0] = *(const int4v*)(smem + bufo + bOff[ni] + offLo);
            b_frag[ni].h[1] = *(const int4v*)(smem + bufo + bOff[ni] + offHi);
        }

        if (t + 2 < NT) {
            // all waves' frag reads must land before buf[t&1] is overwritten
            asm volatile("s_waitcnt lgkmcnt(0)" ::: "memory");
            __builtin_amdgcn_sched_barrier(0);
            __builtin_amdgcn_s_barrier();
            stage(t + 2, bufo);   // async; hidden under the MFMAs below
        }

#pragma unroll
        for (int mi = 0; mi < 4; ++mi)
#pragma unroll
            for (int ni = 0; ni < 4; ++ni)
                acc[mi][ni] = __builtin_amdgcn_mfma_scale_f32_16x16x128_f8f6f4(
                    a_frag[mi].v, b_frag[ni].v, acc[mi][ni],
                    0, 0,                     // cbsz=fp8 e4m3, blgp=fp8 e4m3
                    0, 0x7F7F7F7F,            // A scales: unity E8M0
                    0, 0x7F7F7F7F);           // B scales: unity
    }

    // ---- epilogue (unchanged). C layout: col = l16 (-> n), row = quad*4+reg.
    __syncthreads();  // all waves' ds_reads drained; safe to reuse LDS
    float* wred = (float*)smem + wave * (64 * 20);  // 5120 B per wave

    float s2v[4];
#pragma unroll
    for (int ni = 0; ni < 4; ++ni)
        s2v[ni] = s2[n0 + wn + ni * 16 + l16];

#pragma unroll
    for (int mi = 0; mi < 4; ++mi) {
#pragma unroll
        for (int r = 0; r < 4; ++r) {
            const int rowL = mi * 16 + quad * 4 + r;
            const float xv = x2[m0 + wm + rowL];
            float sum = 0.f;
#pragma unroll
            for (int ni = 0; ni < 4; ++ni) {
                float d2 = xv + s2v[ni] - 2.0f * acc[mi][ni][r];
                d2 = fmaxf(d2, 0.f);
                sum += __expf(-sc * d2);
            }
            wred[rowL * 20 + l16] = sum;
        }
    }
    __syncthreads();  // order LDS writes before cross-lane reads

    float4 p0 = *(float4*)(wred + lane * 20 + 0);
    float4 p1 = *(float4*)(wred + lane * 20 + 4);
    float4 p2 = *(float4*)(wred + lane * 20 + 8);
    float4 p3 = *(float4*)(wred + lane * 20 + 12);
    float s = (p0.x + p0.y + p0.z + p0.w) + (p1.x + p1.y + p1.z + p1.w)
            + (p2.x + p2.y + p2.z + p2.w) + (p3.x + p3.y + p3.z + p3.w);
    atomicAdd(&rowsum[m0 + wm + lane], s);
}

// ---------------------------------------------------------------------------
__global__ void finalize_kernel(const float* __restrict__ rowsum,
                                const float* __restrict__ scale_p,
                                float* __restrict__ out, int M, int N, int Dv) {
    const int m = blockIdx.x * 256 + threadIdx.x;
    if (m < M) {
        const float sc = *scale_p;
        const float cst = -logf((float)N) + 0.5f * (float)Dv * logf(sc / 3.14159265358979f);
        out[m] = logf(rowsum[m]) + cst;
    }
}

// ---------------------------------------------------------------------------
extern "C" void kernel_launch(void* const* d_in, const int* in_sizes, int n_in,
                              void* d_out, int out_size, void* d_ws, size_t ws_size,
                              hipStream_t stream) {
    const float* X       = (const float*)d_in[0];
    const float* S       = (const float*)d_in[1];
    const float* scale_p = (const float*)d_in[2];
    float* out = (float*)d_out;

    const int M  = out_size;            // 8192
    const int Dv = in_sizes[0] / M;     // 512
    const int N  = in_sizes[1] / Dv;    // 8192

    char* ws = (char*)d_ws;
    unsigned char* Xq = (unsigned char*)ws;
    unsigned char* Sq = (unsigned char*)(ws + (size_t)M * Dv);
    float* x2     = (float*)(ws + (size_t)M * Dv + (size_t)N * Dv);
    float* s2     = x2 + M;
    float* rowsum = s2 + N;

    prep_kernel<<<2048, 256, 0, stream>>>(X, S, Xq, Sq, x2, s2, rowsum, M, M + N, Dv);

    dim3 grid(M / BM, N / BN);
    if (Dv == 512)
        kde_gemm_kernel<512><<<grid, 256, 0, stream>>>(Xq, Sq, x2, s2, scale_p, rowsum, M, N, Dv);
    else
        kde_gemm_kernel<0><<<grid, 256, 0, stream>>>(Xq, Sq, x2, s2, scale_p, rowsum, M, N, Dv);

    finalize_kernel<<<(M + 255) / 256, 256, 0, stream>>>(rowsum, scale_p, out, M, N, Dv);
}